// Round 10
// baseline (138.308 us; speedup 1.0000x reference)
//
#include <hip/hip_runtime.h>

typedef unsigned short u16;
typedef unsigned int u32;
typedef unsigned long long u64;
typedef __attribute__((ext_vector_type(8))) short short8;
typedef __attribute__((ext_vector_type(4))) float f32x4;

#define T_ 4096
#define QSCALE 0.18033688f   // (1/8) * log2(e): folded into Q at proj time
#define CH 1                 // key-tiles per chunk (1 -> 2112 blocks, max TLP)
#define SBAT 2112            // sum over A of 4*ceil((A+1)/CH)
#define PSTRIDE 36           // P strip row stride in u16 (72 B: 8B-aligned, bank-uniform)

#if __has_builtin(__builtin_amdgcn_exp2f)
#define EXP2F(x) __builtin_amdgcn_exp2f(x)
#else
#define EXP2F(x) exp2f(x)
#endif

__device__ __forceinline__ u16 f2bf(float f) {
    unsigned u = __float_as_uint(f);
    u += 0x7FFFu + ((u >> 16) & 1u);   // RNE to bf16
    return (u16)(u >> 16);
}

// ---------------------------------------------------------------------------
// Kernel 0: W -> WTf in MFMA-B-fragment-contiguous order.
// ---------------------------------------------------------------------------
__global__ __launch_bounds__(256) void wtrans_kernel(
    const float* __restrict__ Wq, const float* __restrict__ Wk,
    const float* __restrict__ Wv, u16* __restrict__ WTf)
{
    const int tid  = blockIdx.x * 256 + threadIdx.x;   // 48*256 = 12288
    const int frag = tid >> 6;                          // 0..191
    const int lane = tid & 63;
    const int ng   = frag >> 4;
    const int kc   = frag & 15;
    const int m    = ng >> 2;
    const float* W = (m == 0) ? Wq : (m == 1) ? Wk : Wv;
    const int h  = (ng & 3) * 16 + (lane & 15);
    const int c0 = kc * 32 + (lane >> 4) * 8;
    short8 v;
    #pragma unroll
    for (int j = 0; j < 8; ++j)
        v[j] = (short)f2bf(W[(c0 + j) * 64 + h]);
    *(short8*)(WTf + (size_t)frag * 512 + lane * 8) = v;
}

// ---------------------------------------------------------------------------
// Kernel 1: projection. 1024 blocks x 16 rows (4 blocks/CU). x staged to LDS
// bf16 via coalesced float4 loads; B-frags are dense 1KB loads from WTf.
// Q pre-scaled by QSCALE. Epilogue: LDS image, coalesced copy-out.
// (Unchanged from the validated round-9 version.)
// ---------------------------------------------------------------------------
__global__ __launch_bounds__(256) void proj_kernel(
    const float* __restrict__ x, const u16* __restrict__ WTf,
    u16* __restrict__ Qf, u16* __restrict__ Kf, u16* __restrict__ Vf)
{
    __shared__ u16 xs[16 * 520];
    __shared__ u16 img[3072];   // Q @0, K @1024, V @2048 (u16 units)
    const int t    = threadIdx.x;
    const int lane = t & 63;
    const int w    = t >> 6;
    const int l16  = lane & 15;
    const int quad = lane >> 4;
    const int rowbase = blockIdx.x * 16;
    const int bat  = rowbase >> 12;
    const int tloc = rowbase & 4095;

    #pragma unroll
    for (int it = 0; it < 8; ++it) {
        int f   = t + it * 256;                 // float4 index, coalesced
        int row = f >> 7;
        int c4  = (f & 127) * 4;
        f32x4 a = *(const f32x4*)(x + (size_t)(rowbase + row) * 512 + c4);
        unsigned lo = (unsigned)f2bf(a[0]) | ((unsigned)f2bf(a[1]) << 16);
        unsigned hi = (unsigned)f2bf(a[2]) | ((unsigned)f2bf(a[3]) << 16);
        *(uint2*)(xs + row * 520 + c4) = make_uint2(lo, hi);
    }
    __syncthreads();

    f32x4 acc[3];
    #pragma unroll
    for (int nt = 0; nt < 3; ++nt) acc[nt] = (f32x4){0.f, 0.f, 0.f, 0.f};

    const u16* ab = xs + l16 * 520 + quad * 8;
    const u16* wb = WTf + (size_t)(w * 3 * 16) * 512 + lane * 8;

    #pragma unroll 4
    for (int kc = 0; kc < 16; ++kc) {
        short8 af = *(const short8*)(ab + kc * 32);
        #pragma unroll
        for (int nt = 0; nt < 3; ++nt) {
            short8 bf = *(const short8*)(wb + (size_t)(nt * 16 + kc) * 512);
            acc[nt] = __builtin_amdgcn_mfma_f32_16x16x32_bf16(af, bf, acc[nt], 0, 0, 0);
        }
    }

    // ---- epilogue: scatter into LDS image ----
    #pragma unroll
    for (int nt = 0; nt < 3; ++nt) {
        int ng = w * 3 + nt;
        if (ng < 8) {
            int ng4  = ng & 3;
            float sc = (ng < 4) ? QSCALE : 1.0f;
            u16* ib  = img + ((ng < 4) ? 0 : 1024) + (ng4 >> 1) * 512
                          + ((ng4 & 1) * 2 + (l16 >> 3)) * 128 + (l16 & 7);
            #pragma unroll
            for (int i = 0; i < 4; ++i)
                ib[(quad * 4 + i) * 8] = f2bf(acc[nt][i] * sc);
        } else {
            int nt2  = ng - 8;
            unsigned lo = (unsigned)f2bf(acc[nt][0]) | ((unsigned)f2bf(acc[nt][1]) << 16);
            unsigned hi = (unsigned)f2bf(acc[nt][2]) | ((unsigned)f2bf(acc[nt][3]) << 16);
            *(uint2*)(img + 2048 + nt2 * 256 + (quad >> 1) * 128 + l16 * 8
                          + (quad & 1) * 4) = make_uint2(lo, hi);
        }
    }
    __syncthreads();

    // ---- coalesced copy-out ----
    const int tb   = tloc >> 4;
    const int kt   = tloc >> 7;
    const int ks   = (tloc >> 5) & 3;
    const int half = (tloc >> 4) & 1;
    uint2 vq = *(uint2*)(img + t * 4);
    uint2 vk = *(uint2*)(img + 1024 + t * 4);
    uint2 vv = *(uint2*)(img + 2048 + t * 4);
    *(uint2*)(Qf + (size_t)(bat * 256 + tb) * 1024 + t * 4) = vq;
    *(uint2*)(Kf + (size_t)(bat * 256 + tb) * 1024 + t * 4) = vk;
    const int nt2c = t >> 6;
    *(uint2*)(Vf + (size_t)((bat * 32 + kt) * 4 + ks) * 2048
                 + nt2c * 512 + half * 256 + (t & 63) * 4) = vv;
}

// ---------------------------------------------------------------------------
// Kernel 2: XCD-pinned, barrier-free K-split attention. One wave = one
// (bat, q32, single key-tile) task (CH=1: straight-line body, max ILP/TLP).
// P^T transpose via per-wave LDS strip (in-order DS pipe, no barrier).
// den computed on the MFMA pipe with a constant-ones A-fragment (replicated
// across rows -> no shuffle reduce). cc==1 groups write final output
// directly; cc>1 groups nt-store bf16 partials for fin. NO device fences.
// ---------------------------------------------------------------------------
__global__ __launch_bounds__(256, 4) void attn_kernel(
    const u16* __restrict__ Qf, const u16* __restrict__ Kf,
    const u16* __restrict__ Vf, u32* __restrict__ pnum,
    float* __restrict__ pden, float* __restrict__ out)
{
    __shared__ u16 Ps[4][2][16 * PSTRIDE];   // [wave][g][q*PSTRIDE + s], 9.2 KB

    const int w    = threadIdx.x >> 6;
    const int lane = threadIdx.x & 63;
    const int l16  = lane & 15;
    const int qd   = lane >> 4;
    const int xcd  = blockIdx.x & 7;
    const int bat  = xcd >> 1;
    const int tw   = ((blockIdx.x >> 3) * 2 + (xcd & 1)) * 4 + w;  // 0..SBAT-1

    int A = 31, pre = 0, cc = 1;
    for (;;) {                               // big-A first
        cc = (A + CH) / CH;
        int cnt4 = 4 * cc;
        if (tw < pre + cnt4) break;
        pre += cnt4; --A;
    }
    const int r    = tw - pre;
    const int c    = r >> 2;                 // my chunk (shared by 4 waves)
    const int b_   = r & 3;
    const int nkt  = A + 1;
    const int q32  = 4 * A + b_;
    const int kt0  = c * CH;
    const int kt1  = min(kt0 + CH, nkt);
    const int slot = bat * SBAT + pre + b_ + 4 * c;   // chunk stride 4

    short8 aq[2][2];
    #pragma unroll
    for (int g = 0; g < 2; ++g)
        #pragma unroll
        for (int f = 0; f < 2; ++f)
            aq[g][f] = *(const short8*)(Qf
                + ((size_t)((bat * 256 + q32 * 2 + g) * 2 + f)) * 512 + lane * 8);

    // constant-ones A-fragment for the den MFMA (bf16 1.0 = 0x3F80)
    short8 ones;
    #pragma unroll
    for (int j = 0; j < 8; ++j) ones[j] = (short)0x3F80;

    f32x4 acc[2][4];
    f32x4 accden[2];
    #pragma unroll
    for (int g = 0; g < 2; ++g) {
        accden[g] = (f32x4){0.f, 0.f, 0.f, 0.f};
        for (int n = 0; n < 4; ++n) acc[g][n] = (f32x4){0.f, 0.f, 0.f, 0.f};
    }

    // per-wave P strip base pointers (row q = l16, col s; u64-aligned writes)
    u16* Pw[2] = { &Ps[w][0][0], &Ps[w][1][0] };

    for (int kt = kt0; kt < kt1; ++kt) {
        const u16* kfb = Kf + ((size_t)(bat * 256 + kt * 8) * 2) * 512 + lane * 8;
        const u16* vfb = Vf + ((size_t)((bat * 32 + kt) * 16)) * 512 + lane * 8;
        #pragma unroll
        for (int ks = 0; ks < 4; ++ks) {
            // ---- S^T = K*Q^T -> exp -> pack -> LDS strip (write phase) ----
            #pragma unroll
            for (int b = 0; b < 2; ++b) {
                int nt = 2 * ks + b;
                short8 k0 = *(const short8*)(kfb + (size_t)nt * 1024);
                short8 k1 = *(const short8*)(kfb + (size_t)nt * 1024 + 512);
                #pragma unroll
                for (int g = 0; g < 2; ++g) {
                    f32x4 st = (f32x4){0.f, 0.f, 0.f, 0.f};
                    st = __builtin_amdgcn_mfma_f32_16x16x32_bf16(k0, aq[g][0], st, 0, 0, 0);
                    st = __builtin_amdgcn_mfma_f32_16x16x32_bf16(k1, aq[g][1], st, 0, 0, 0);
                    float p0 = EXP2F(st[0]);   // Q pre-scaled: exp2 direct
                    float p1 = EXP2F(st[1]);
                    float p2 = EXP2F(st[2]);
                    float p3 = EXP2F(st[3]);
                    u32 q01 = __builtin_amdgcn_perm(__float_as_uint(p1), __float_as_uint(p0), 0x07060302u);
                    u32 q23 = __builtin_amdgcn_perm(__float_as_uint(p3), __float_as_uint(p2), 0x07060302u);
                    // strip[g][q=l16][s = b*16 + qd*4 .. +4] <- p0..p3 (trunc bf16)
                    u64 pv = (u64)q01 | ((u64)q23 << 32);
                    *(u64*)(Pw[g] + l16 * PSTRIDE + b * 16 + qd * 4) = pv;
                }
            }
            // ---- P^T B-frags from strip (read phase; same-wave, in-order DS) ----
            short8 ap[2];
            #pragma unroll
            for (int g = 0; g < 2; ++g)
                ap[g] = *(const short8*)(Pw[g] + l16 * PSTRIDE + qd * 8);
            // ---- den on the MFMA pipe: D[m][q] = sum_k P^T[k][q] ----
            accden[0] = __builtin_amdgcn_mfma_f32_16x16x32_bf16(ones, ap[0], accden[0], 0, 0, 0);
            accden[1] = __builtin_amdgcn_mfma_f32_16x16x32_bf16(ones, ap[1], accden[1], 0, 0, 0);
            // ---- O^T += V^T * P^T ----
            #pragma unroll
            for (int nt2 = 0; nt2 < 4; ++nt2) {
                short8 av = *(const short8*)(vfb + (size_t)(ks * 4 + nt2) * 512);
                acc[0][nt2] = __builtin_amdgcn_mfma_f32_16x16x32_bf16(av, ap[0], acc[0][nt2], 0, 0, 0);
                acc[1][nt2] = __builtin_amdgcn_mfma_f32_16x16x32_bf16(av, ap[1], acc[1][nt2], 0, 0, 0);
            }
        }
    }

    // den is replicated across rows by the ones-MFMA: lane-local, no reduce
    float den[2] = { accden[0][0], accden[1][0] };

    if (cc == 1) {
        // single chunk: finalize directly (sole writer of these rows)
        const float rd0 = 1.0f / den[0];
        const float rd1 = 1.0f / den[1];
        float* op = out + ((size_t)(bat * T_ + q32 * 32 + l16)) * 64 + qd * 4;
        #pragma unroll
        for (int g = 0; g < 2; ++g) {
            const float rd = g ? rd1 : rd0;
            #pragma unroll
            for (int nt2 = 0; nt2 < 4; ++nt2) {
                f32x4 v;
                #pragma unroll
                for (int i = 0; i < 4; ++i) v[i] = acc[g][nt2][i] * rd;
                *(f32x4*)(op + (size_t)g * 16 * 64 + nt2 * 16) = v;
            }
        }
    } else {
        // flush: dense nt u64 stores to deterministic slot
        u32* np = pnum + (size_t)slot * 1024;
        #pragma unroll
        for (int g = 0; g < 2; ++g)
            #pragma unroll
            for (int nt2 = 0; nt2 < 4; ++nt2) {
                u32 lo = (u32)f2bf(acc[g][nt2][0]) | ((u32)f2bf(acc[g][nt2][1]) << 16);
                u32 hi = (u32)f2bf(acc[g][nt2][2]) | ((u32)f2bf(acc[g][nt2][3]) << 16);
                u64 val = (u64)lo | ((u64)hi << 32);
                __builtin_nontemporal_store(val, (u64*)(np + (g * 4 + nt2) * 128 + lane * 2));
            }
        if (lane < 32)
            __builtin_nontemporal_store(den[lane >> 4],
                                        &pden[(size_t)slot * 32 + lane]);
    }
}

// ---------------------------------------------------------------------------
// Kernel 3: finalize — sum partial slots (chunk stride 4 in slot space),
// divide, write out. cc==1 groups (A==0) already written by attn.
// ---------------------------------------------------------------------------
__global__ __launch_bounds__(256) void fin_kernel(
    const u32* __restrict__ pnum, const float* __restrict__ pden,
    float* __restrict__ out)
{
    __shared__ float rden[32];
    const int bq  = blockIdx.x;            // bat*128 + q32
    const int bat = bq >> 7;
    const int q32 = bq & 127;
    const int A = q32 >> 2, b = q32 & 3;
    const int cc = (A + CH) / CH;
    if (cc == 1) return;                   // written directly by attn
    int pre = 0;
    for (int j = 31; j > A; --j) pre += 4 * ((j + CH) / CH);
    const int base = bat * SBAT + pre + b;   // chunk ci at base + 4*ci

    if (threadIdx.x < 32) {
        float d = 0.f;
        for (int ci = 0; ci < cc; ++ci)
            d += pden[(size_t)(base + 4 * ci) * 32 + threadIdx.x];
        rden[threadIdx.x] = 1.0f / d;
    }
    __syncthreads();

    const int m   = threadIdx.x >> 3;       // out row 0..31
    const int g   = m >> 4;
    const int l16 = m & 15;
    const int h0  = (threadIdx.x & 7) * 8;
    const int nt2 = h0 >> 4;
    const int q0  = (h0 >> 2) & 3;
    const int off = (g * 4 + nt2) * 128 + q0 * 32 + l16 * 2;

    float sv[8];
    #pragma unroll
    for (int e = 0; e < 8; ++e) sv[e] = 0.f;
    for (int ci = 0; ci < cc; ++ci) {
        const u32* sp = pnum + (size_t)(base + 4 * ci) * 1024 + off;
        uint2 a  = *(const uint2*)(sp);
        uint2 bb = *(const uint2*)(sp + 32);
        u32 vals[4] = {a.x, a.y, bb.x, bb.y};
        #pragma unroll
        for (int e = 0; e < 4; ++e) {
            sv[2 * e]     += __uint_as_float(vals[e] << 16);
            sv[2 * e + 1] += __uint_as_float(vals[e] & 0xFFFF0000u);
        }
    }
    const float rd = rden[m];
    float* op = out + (size_t)(bat * T_ + q32 * 32 + m) * 64 + h0;
    f32x4 r0, r1;
    #pragma unroll
    for (int i = 0; i < 4; ++i) { r0[i] = sv[i] * rd; r1[i] = sv[4 + i] * rd; }
    *(f32x4*)(op)     = r0;
    *(f32x4*)(op + 4) = r1;
}

// ---------------------------------------------------------------------------
extern "C" void kernel_launch(void* const* d_in, const int* in_sizes, int n_in,
                              void* d_out, int out_size, void* d_ws, size_t ws_size,
                              hipStream_t stream)
{
    const float* x  = (const float*)d_in[0];
    const float* Wk = (const float*)d_in[1];
    const float* Wq = (const float*)d_in[2];
    const float* Wv = (const float*)d_in[3];
    float* out = (float*)d_out;

    u16* ws  = (u16*)d_ws;
    u16* WTf = ws;                          // 98304 u16 (padded to 131072)
    u16* Qf  = ws + 131072;                 // 1048576 u16 each
    u16* Kf  = Qf + 1048576;
    u16* Vf  = Kf + 1048576;
    u32*   pnum = (u32*)(Vf + 1048576);     // 4*SBAT*1024 u32  (~34.6 MB)
    float* pden = (float*)(pnum + (size_t)4 * SBAT * 1024);   // 4*SBAT*32 f32

    wtrans_kernel<<<48, 256, 0, stream>>>(Wq, Wk, Wv, WTf);
    proj_kernel<<<1024, 256, 0, stream>>>(x, WTf, Qf, Kf, Vf);
    attn_kernel<<<SBAT, 256, 0, stream>>>(Qf, Kf, Vf, pnum, pden, out);
    fin_kernel<<<512, 256, 0, stream>>>(pnum, pden, out);
}

// Round 11
// 122.306 us; speedup vs baseline: 1.1308x; 1.1308x over previous
//
#include <hip/hip_runtime.h>

typedef unsigned short u16;
typedef unsigned int u32;
typedef unsigned long long u64;
typedef __attribute__((ext_vector_type(8))) short short8;
typedef __attribute__((ext_vector_type(4))) float f32x4;

#define T_ 4096
#define QSCALE 0.18033688f   // (1/8) * log2(e): folded into Q at proj time
#define CH 2                 // key-tiles per chunk (proven sweet spot)
#define SBAT 1088            // sum over A of 4*ceil((A+1)/CH)
#define PSTRIDE 36           // P strip row stride in u16 (72 B: 8B-aligned, bank-uniform)

#if __has_builtin(__builtin_amdgcn_exp2f)
#define EXP2F(x) __builtin_amdgcn_exp2f(x)
#else
#define EXP2F(x) exp2f(x)
#endif

__device__ __forceinline__ u16 f2bf(float f) {
    unsigned u = __float_as_uint(f);
    u += 0x7FFFu + ((u >> 16) & 1u);   // RNE to bf16
    return (u16)(u >> 16);
}

// ---------------------------------------------------------------------------
// Kernel 0: W -> WTf in MFMA-B-fragment-contiguous order.
// ---------------------------------------------------------------------------
__global__ __launch_bounds__(256) void wtrans_kernel(
    const float* __restrict__ Wq, const float* __restrict__ Wk,
    const float* __restrict__ Wv, u16* __restrict__ WTf)
{
    const int tid  = blockIdx.x * 256 + threadIdx.x;   // 48*256 = 12288
    const int frag = tid >> 6;                          // 0..191
    const int lane = tid & 63;
    const int ng   = frag >> 4;
    const int kc   = frag & 15;
    const int m    = ng >> 2;
    const float* W = (m == 0) ? Wq : (m == 1) ? Wk : Wv;
    const int h  = (ng & 3) * 16 + (lane & 15);
    const int c0 = kc * 32 + (lane >> 4) * 8;
    short8 v;
    #pragma unroll
    for (int j = 0; j < 8; ++j)
        v[j] = (short)f2bf(W[(c0 + j) * 64 + h]);
    *(short8*)(WTf + (size_t)frag * 512 + lane * 8) = v;
}

// ---------------------------------------------------------------------------
// Kernel 1: projection. 1024 blocks x 16 rows (4 blocks/CU). x staged to LDS
// bf16 via coalesced float4 loads; B-frags are dense 1KB loads from WTf.
// Q pre-scaled by QSCALE. Epilogue: LDS image, coalesced copy-out.
// (Unchanged from the validated round-9 version.)
// ---------------------------------------------------------------------------
__global__ __launch_bounds__(256) void proj_kernel(
    const float* __restrict__ x, const u16* __restrict__ WTf,
    u16* __restrict__ Qf, u16* __restrict__ Kf, u16* __restrict__ Vf)
{
    __shared__ u16 xs[16 * 520];
    __shared__ u16 img[3072];   // Q @0, K @1024, V @2048 (u16 units)
    const int t    = threadIdx.x;
    const int lane = t & 63;
    const int w    = t >> 6;
    const int l16  = lane & 15;
    const int quad = lane >> 4;
    const int rowbase = blockIdx.x * 16;
    const int bat  = rowbase >> 12;
    const int tloc = rowbase & 4095;

    #pragma unroll
    for (int it = 0; it < 8; ++it) {
        int f   = t + it * 256;                 // float4 index, coalesced
        int row = f >> 7;
        int c4  = (f & 127) * 4;
        f32x4 a = *(const f32x4*)(x + (size_t)(rowbase + row) * 512 + c4);
        unsigned lo = (unsigned)f2bf(a[0]) | ((unsigned)f2bf(a[1]) << 16);
        unsigned hi = (unsigned)f2bf(a[2]) | ((unsigned)f2bf(a[3]) << 16);
        *(uint2*)(xs + row * 520 + c4) = make_uint2(lo, hi);
    }
    __syncthreads();

    f32x4 acc[3];
    #pragma unroll
    for (int nt = 0; nt < 3; ++nt) acc[nt] = (f32x4){0.f, 0.f, 0.f, 0.f};

    const u16* ab = xs + l16 * 520 + quad * 8;
    const u16* wb = WTf + (size_t)(w * 3 * 16) * 512 + lane * 8;

    #pragma unroll 4
    for (int kc = 0; kc < 16; ++kc) {
        short8 af = *(const short8*)(ab + kc * 32);
        #pragma unroll
        for (int nt = 0; nt < 3; ++nt) {
            short8 bf = *(const short8*)(wb + (size_t)(nt * 16 + kc) * 512);
            acc[nt] = __builtin_amdgcn_mfma_f32_16x16x32_bf16(af, bf, acc[nt], 0, 0, 0);
        }
    }

    // ---- epilogue: scatter into LDS image ----
    #pragma unroll
    for (int nt = 0; nt < 3; ++nt) {
        int ng = w * 3 + nt;
        if (ng < 8) {
            int ng4  = ng & 3;
            float sc = (ng < 4) ? QSCALE : 1.0f;
            u16* ib  = img + ((ng < 4) ? 0 : 1024) + (ng4 >> 1) * 512
                          + ((ng4 & 1) * 2 + (l16 >> 3)) * 128 + (l16 & 7);
            #pragma unroll
            for (int i = 0; i < 4; ++i)
                ib[(quad * 4 + i) * 8] = f2bf(acc[nt][i] * sc);
        } else {
            int nt2  = ng - 8;
            unsigned lo = (unsigned)f2bf(acc[nt][0]) | ((unsigned)f2bf(acc[nt][1]) << 16);
            unsigned hi = (unsigned)f2bf(acc[nt][2]) | ((unsigned)f2bf(acc[nt][3]) << 16);
            *(uint2*)(img + 2048 + nt2 * 256 + (quad >> 1) * 128 + l16 * 8
                          + (quad & 1) * 4) = make_uint2(lo, hi);
        }
    }
    __syncthreads();

    // ---- coalesced copy-out ----
    const int tb   = tloc >> 4;
    const int kt   = tloc >> 7;
    const int ks   = (tloc >> 5) & 3;
    const int half = (tloc >> 4) & 1;
    uint2 vq = *(uint2*)(img + t * 4);
    uint2 vk = *(uint2*)(img + 1024 + t * 4);
    uint2 vv = *(uint2*)(img + 2048 + t * 4);
    *(uint2*)(Qf + (size_t)(bat * 256 + tb) * 1024 + t * 4) = vq;
    *(uint2*)(Kf + (size_t)(bat * 256 + tb) * 1024 + t * 4) = vk;
    const int nt2c = t >> 6;
    *(uint2*)(Vf + (size_t)((bat * 32 + kt) * 4 + ks) * 2048
                 + nt2c * 512 + half * 256 + (t & 63) * 4) = vv;
}

// ---------------------------------------------------------------------------
// Kernel 2: XCD-pinned, barrier-free K-split attention (CH=2, the proven
// task shape). One wave = one (bat, q32, chunk of <=2 key tiles); the <=2
// iterations are explicitly straight-lined so the 2nd tile's K/V loads issue
// during the 1st tile's MFMA chain. P^T transpose via per-wave LDS strip
// (in-order DS pipe, no barrier). den on the MFMA pipe via ones-fragment
// (verified bit-identical). cc==1 writes final output directly; cc>1
// nt-stores bf16 partials for fin. NO device-scope fences.
// ---------------------------------------------------------------------------
__global__ __launch_bounds__(256, 4) void attn_kernel(
    const u16* __restrict__ Qf, const u16* __restrict__ Kf,
    const u16* __restrict__ Vf, u32* __restrict__ pnum,
    float* __restrict__ pden, float* __restrict__ out)
{
    __shared__ u16 Ps[4][2][16 * PSTRIDE];   // [wave][g][q*PSTRIDE + s], 9.2 KB

    const int w    = threadIdx.x >> 6;
    const int lane = threadIdx.x & 63;
    const int l16  = lane & 15;
    const int qd   = lane >> 4;
    const int xcd  = blockIdx.x & 7;
    const int bat  = xcd >> 1;
    const int tw   = ((blockIdx.x >> 3) * 2 + (xcd & 1)) * 4 + w;  // 0..SBAT-1

    int A = 31, pre = 0, cc = 1;
    for (;;) {                               // big-A first
        cc = (A + CH) / CH;
        int cnt4 = 4 * cc;
        if (tw < pre + cnt4) break;
        pre += cnt4; --A;
    }
    const int r    = tw - pre;
    const int c    = r >> 2;                 // my chunk (shared by 4 waves)
    const int b_   = r & 3;
    const int nkt  = A + 1;
    const int q32  = 4 * A + b_;
    const int kt0  = c * CH;
    const int kt1  = min(kt0 + CH, nkt);
    const int slot = bat * SBAT + pre + b_ + 4 * c;   // chunk stride 4

    short8 aq[2][2];
    #pragma unroll
    for (int g = 0; g < 2; ++g)
        #pragma unroll
        for (int f = 0; f < 2; ++f)
            aq[g][f] = *(const short8*)(Qf
                + ((size_t)((bat * 256 + q32 * 2 + g) * 2 + f)) * 512 + lane * 8);

    // constant-ones A-fragment for the den MFMA (bf16 1.0 = 0x3F80)
    short8 ones;
    #pragma unroll
    for (int j = 0; j < 8; ++j) ones[j] = (short)0x3F80;

    f32x4 acc[2][4];
    f32x4 accden[2];
    #pragma unroll
    for (int g = 0; g < 2; ++g) {
        accden[g] = (f32x4){0.f, 0.f, 0.f, 0.f};
        for (int n = 0; n < 4; ++n) acc[g][n] = (f32x4){0.f, 0.f, 0.f, 0.f};
    }

    // per-wave P strip base pointers (row q = l16, col s; u64-aligned writes)
    u16* Pw[2] = { &Ps[w][0][0], &Ps[w][1][0] };

    auto body = [&](int kt) __attribute__((always_inline)) {
        const u16* kfb = Kf + ((size_t)(bat * 256 + kt * 8) * 2) * 512 + lane * 8;
        const u16* vfb = Vf + ((size_t)((bat * 32 + kt) * 16)) * 512 + lane * 8;
        #pragma unroll
        for (int ks = 0; ks < 4; ++ks) {
            // ---- S^T = K*Q^T -> exp -> pack -> LDS strip (write phase) ----
            #pragma unroll
            for (int b = 0; b < 2; ++b) {
                int nt = 2 * ks + b;
                short8 k0 = *(const short8*)(kfb + (size_t)nt * 1024);
                short8 k1 = *(const short8*)(kfb + (size_t)nt * 1024 + 512);
                #pragma unroll
                for (int g = 0; g < 2; ++g) {
                    f32x4 st = (f32x4){0.f, 0.f, 0.f, 0.f};
                    st = __builtin_amdgcn_mfma_f32_16x16x32_bf16(k0, aq[g][0], st, 0, 0, 0);
                    st = __builtin_amdgcn_mfma_f32_16x16x32_bf16(k1, aq[g][1], st, 0, 0, 0);
                    float p0 = EXP2F(st[0]);   // Q pre-scaled: exp2 direct
                    float p1 = EXP2F(st[1]);
                    float p2 = EXP2F(st[2]);
                    float p3 = EXP2F(st[3]);
                    u32 q01 = __builtin_amdgcn_perm(__float_as_uint(p1), __float_as_uint(p0), 0x07060302u);
                    u32 q23 = __builtin_amdgcn_perm(__float_as_uint(p3), __float_as_uint(p2), 0x07060302u);
                    // strip[g][q=l16][s = b*16 + qd*4 .. +4] <- p0..p3 (trunc bf16)
                    u64 pv = (u64)q01 | ((u64)q23 << 32);
                    *(u64*)(Pw[g] + l16 * PSTRIDE + b * 16 + qd * 4) = pv;
                }
            }
            // ---- P^T B-frags from strip (read phase; same-wave, in-order DS) ----
            short8 ap[2];
            #pragma unroll
            for (int g = 0; g < 2; ++g)
                ap[g] = *(const short8*)(Pw[g] + l16 * PSTRIDE + qd * 8);
            // ---- den on the MFMA pipe: D[m][q] = sum_k P^T[k][q] ----
            accden[0] = __builtin_amdgcn_mfma_f32_16x16x32_bf16(ones, ap[0], accden[0], 0, 0, 0);
            accden[1] = __builtin_amdgcn_mfma_f32_16x16x32_bf16(ones, ap[1], accden[1], 0, 0, 0);
            // ---- O^T += V^T * P^T ----
            #pragma unroll
            for (int nt2 = 0; nt2 < 4; ++nt2) {
                short8 av = *(const short8*)(vfb + (size_t)(ks * 4 + nt2) * 512);
                acc[0][nt2] = __builtin_amdgcn_mfma_f32_16x16x32_bf16(av, ap[0], acc[0][nt2], 0, 0, 0);
                acc[1][nt2] = __builtin_amdgcn_mfma_f32_16x16x32_bf16(av, ap[1], acc[1][nt2], 0, 0, 0);
            }
        }
    };

    // straight-line the <=2 key-tile iterations (no dynamic loop)
    body(kt0);
    if (kt0 + 1 < kt1) body(kt0 + 1);

    // den is replicated across rows by the ones-MFMA: lane-local, no reduce
    float den[2] = { accden[0][0], accden[1][0] };

    if (cc == 1) {
        // single chunk: finalize directly (sole writer of these rows)
        const float rd0 = 1.0f / den[0];
        const float rd1 = 1.0f / den[1];
        float* op = out + ((size_t)(bat * T_ + q32 * 32 + l16)) * 64 + qd * 4;
        #pragma unroll
        for (int g = 0; g < 2; ++g) {
            const float rd = g ? rd1 : rd0;
            #pragma unroll
            for (int nt2 = 0; nt2 < 4; ++nt2) {
                f32x4 v;
                #pragma unroll
                for (int i = 0; i < 4; ++i) v[i] = acc[g][nt2][i] * rd;
                *(f32x4*)(op + (size_t)g * 16 * 64 + nt2 * 16) = v;
            }
        }
    } else {
        // flush: dense nt u64 stores to deterministic slot
        u32* np = pnum + (size_t)slot * 1024;
        #pragma unroll
        for (int g = 0; g < 2; ++g)
            #pragma unroll
            for (int nt2 = 0; nt2 < 4; ++nt2) {
                u32 lo = (u32)f2bf(acc[g][nt2][0]) | ((u32)f2bf(acc[g][nt2][1]) << 16);
                u32 hi = (u32)f2bf(acc[g][nt2][2]) | ((u32)f2bf(acc[g][nt2][3]) << 16);
                u64 val = (u64)lo | ((u64)hi << 32);
                __builtin_nontemporal_store(val, (u64*)(np + (g * 4 + nt2) * 128 + lane * 2));
            }
        if (lane < 32)
            __builtin_nontemporal_store(den[lane >> 4],
                                        &pden[(size_t)slot * 32 + lane]);
    }
}

// ---------------------------------------------------------------------------
// Kernel 3: finalize — sum partial slots (chunk stride 4 in slot space),
// divide, write out. cc==1 groups (A==0) already written by attn.
// ---------------------------------------------------------------------------
__global__ __launch_bounds__(256) void fin_kernel(
    const u32* __restrict__ pnum, const float* __restrict__ pden,
    float* __restrict__ out)
{
    __shared__ float rden[32];
    const int bq  = blockIdx.x;            // bat*128 + q32
    const int bat = bq >> 7;
    const int q32 = bq & 127;
    const int A = q32 >> 2, b = q32 & 3;
    const int cc = (A + CH) / CH;
    if (cc == 1) return;                   // written directly by attn
    int pre = 0;
    for (int j = 31; j > A; --j) pre += 4 * ((j + CH) / CH);
    const int base = bat * SBAT + pre + b;   // chunk ci at base + 4*ci

    if (threadIdx.x < 32) {
        float d = 0.f;
        for (int ci = 0; ci < cc; ++ci)
            d += pden[(size_t)(base + 4 * ci) * 32 + threadIdx.x];
        rden[threadIdx.x] = 1.0f / d;
    }
    __syncthreads();

    const int m   = threadIdx.x >> 3;       // out row 0..31
    const int g   = m >> 4;
    const int l16 = m & 15;
    const int h0  = (threadIdx.x & 7) * 8;
    const int nt2 = h0 >> 4;
    const int q0  = (h0 >> 2) & 3;
    const int off = (g * 4 + nt2) * 128 + q0 * 32 + l16 * 2;

    float sv[8];
    #pragma unroll
    for (int e = 0; e < 8; ++e) sv[e] = 0.f;
    for (int ci = 0; ci < cc; ++ci) {
        const u32* sp = pnum + (size_t)(base + 4 * ci) * 1024 + off;
        uint2 a  = *(const uint2*)(sp);
        uint2 bb = *(const uint2*)(sp + 32);
        u32 vals[4] = {a.x, a.y, bb.x, bb.y};
        #pragma unroll
        for (int e = 0; e < 4; ++e) {
            sv[2 * e]     += __uint_as_float(vals[e] << 16);
            sv[2 * e + 1] += __uint_as_float(vals[e] & 0xFFFF0000u);
        }
    }
    const float rd = rden[m];
    float* op = out + (size_t)(bat * T_ + q32 * 32 + m) * 64 + h0;
    f32x4 r0, r1;
    #pragma unroll
    for (int i = 0; i < 4; ++i) { r0[i] = sv[i] * rd; r1[i] = sv[4 + i] * rd; }
    *(f32x4*)(op)     = r0;
    *(f32x4*)(op + 4) = r1;
}

// ---------------------------------------------------------------------------
extern "C" void kernel_launch(void* const* d_in, const int* in_sizes, int n_in,
                              void* d_out, int out_size, void* d_ws, size_t ws_size,
                              hipStream_t stream)
{
    const float* x  = (const float*)d_in[0];
    const float* Wk = (const float*)d_in[1];
    const float* Wq = (const float*)d_in[2];
    const float* Wv = (const float*)d_in[3];
    float* out = (float*)d_out;

    u16* ws  = (u16*)d_ws;
    u16* WTf = ws;                          // 98304 u16 (padded to 131072)
    u16* Qf  = ws + 131072;                 // 1048576 u16 each
    u16* Kf  = Qf + 1048576;
    u16* Vf  = Kf + 1048576;
    u32*   pnum = (u32*)(Vf + 1048576);     // 4*SBAT*1024 u32  (~17.8 MB)
    float* pden = (float*)(pnum + (size_t)4 * SBAT * 1024);   // 4*SBAT*32 f32

    wtrans_kernel<<<48, 256, 0, stream>>>(Wq, Wk, Wv, WTf);
    proj_kernel<<<1024, 256, 0, stream>>>(x, WTf, Qf, Kf, Vf);
    attn_kernel<<<SBAT, 256, 0, stream>>>(Qf, Kf, Vf, pnum, pden, out);
    fin_kernel<<<512, 256, 0, stream>>>(pnum, pden, out);
}